// Round 3
// baseline (99.299 us; speedup 1.0000x reference)
//
#include <hip/hip_runtime.h>
#include <hip/hip_bf16.h>

// Sizes fixed by the reference
#define V 50000
#define D 256
#define B 256
#define C 10
#define TWO_D 512
#define VBLK 32
#define NBLK ((V + VBLK - 1) / VBLK)   // 1563
#define MPAD 4096                      // 256 b * 16 (c padded 10 -> 16)

typedef __bf16 bf16x8 __attribute__((ext_vector_type(8)));
typedef float f32x4 __attribute__((ext_vector_type(4)));
typedef unsigned short ushort_t;
typedef unsigned int uint_t;

__device__ inline ushort_t f2bf(float f) {
    uint_t u = __builtin_bit_cast(uint_t, f);
    uint_t r = (u + 0x7FFFu + ((u >> 16) & 1u)) >> 16;
    return (ushort_t)r;
}

__device__ inline float softplus_f(float x) {
    return (x > 0.f) ? (x + log1pf(__expf(-x))) : log1pf(__expf(x));
}

__device__ inline float wave_reduce(float v) {
    #pragma unroll
    for (int m = 1; m < 64; m <<= 1) v += __shfl_xor(v, m);
    return v;
}

// ---------------------------------------------------------------------------
// K0: build X_bf [4096 x 512]: row m = b*16+c -> [center_b | ctx_{b,c}] bf16.
// ---------------------------------------------------------------------------
__global__ __launch_bounds__(256) void k0_gather(
    const int* __restrict__ center_id, const int* __restrict__ context_ids,
    const float* __restrict__ embeddings, ushort_t* __restrict__ xbf)
{
    const int idx = blockIdx.x * 256 + threadIdx.x;  // float4 index
    const int m = idx >> 7;
    const int q = idx & 127;
    const int k = q * 4;
    const int b = m >> 4, c = m & 15;
    ushort4 o;
    if (k < D) {
        const float4 v = *(const float4*)(embeddings + center_id[b] * D + k);
        o.x = f2bf(v.x); o.y = f2bf(v.y); o.z = f2bf(v.z); o.w = f2bf(v.w);
    } else if (c < C) {
        const float4 v = *(const float4*)(embeddings + context_ids[b * C + c] * D + (k - D));
        o.x = f2bf(v.x); o.y = f2bf(v.y); o.z = f2bf(v.z); o.w = f2bf(v.w);
    } else {
        o.x = 0; o.y = 0; o.z = 0; o.w = 0;
    }
    *(ushort4*)(xbf + idx * 4) = o;
}

// ---------------------------------------------------------------------------
// K_enc: MFMA GEMM + fused bias/relu/c-sum -> h_bf[b][e]. (unchanged)
// ---------------------------------------------------------------------------
__global__ __launch_bounds__(256) void k_enc(
    const float* __restrict__ enc_W, const float* __restrict__ enc_b,
    const ushort_t* __restrict__ xbf, ushort_t* __restrict__ h_bf)
{
    __shared__ __align__(16) ushort_t wt[2][64 * 40];
    const int tid = threadIdx.x;
    const int mblk = blockIdx.x & 63;
    const int nblk = blockIdx.x >> 6;
    const int n0 = nblk * 64;
    const int wid = tid >> 6, lane = tid & 63;
    const int l15 = lane & 15, g = lane >> 4;

    const int r0 = tid >> 3, kq = tid & 7, r1 = r0 + 32;
    const float* src0 = enc_W + (n0 + r0) * TWO_D + kq * 4;
    const float* src1 = enc_W + (n0 + r1) * TWO_D + kq * 4;
    const int dst0 = r0 * 40 + kq * 4;
    const int dst1 = r1 * 40 + kq * 4;

    {
        const float4 na = *(const float4*)(src0);
        const float4 nb = *(const float4*)(src1);
        ushort4 pa, pb;
        pa.x = f2bf(na.x); pa.y = f2bf(na.y); pa.z = f2bf(na.z); pa.w = f2bf(na.w);
        pb.x = f2bf(nb.x); pb.y = f2bf(nb.y); pb.z = f2bf(nb.z); pb.w = f2bf(nb.w);
        *(ushort4*)(&wt[0][dst0]) = pa;
        *(ushort4*)(&wt[0][dst1]) = pb;
    }
    __syncthreads();

    const int rowA = mblk * 64 + wid * 16 + l15;
    f32x4 acc[4] = {};
    #pragma unroll 1
    for (int kk = 0; kk < 16; ++kk) {
        const int cur = kk & 1, nxt = cur ^ 1;
        float4 na, nb;
        if (kk < 15) {
            na = *(const float4*)(src0 + (kk + 1) * 32);
            nb = *(const float4*)(src1 + (kk + 1) * 32);
        }
        const bf16x8 A = *(const bf16x8*)(xbf + rowA * TWO_D + kk * 32 + g * 8);
        bf16x8 Bf[4];
        #pragma unroll
        for (int vt = 0; vt < 4; ++vt)
            Bf[vt] = *(const bf16x8*)(&wt[cur][(vt * 16 + l15) * 40 + g * 8]);
        #pragma unroll
        for (int vt = 0; vt < 4; ++vt)
            acc[vt] = __builtin_amdgcn_mfma_f32_16x16x32_bf16(A, Bf[vt], acc[vt], 0, 0, 0);
        if (kk < 15) {
            ushort4 pa, pb;
            pa.x = f2bf(na.x); pa.y = f2bf(na.y); pa.z = f2bf(na.z); pa.w = f2bf(na.w);
            pb.x = f2bf(nb.x); pb.y = f2bf(nb.y); pb.z = f2bf(nb.z); pb.w = f2bf(nb.w);
            *(ushort4*)(&wt[nxt][dst0]) = pa;
            *(ushort4*)(&wt[nxt][dst1]) = pb;
        }
        __syncthreads();
    }

    const int b = mblk * 4 + wid;
    #pragma unroll
    for (int vt = 0; vt < 4; ++vt) {
        const int j = n0 + vt * 16 + l15;
        const float bias = enc_b[j];
        float s = 0.f;
        #pragma unroll
        for (int r = 0; r < 4; ++r) {
            const int c = g * 4 + r;
            const float vv = acc[vt][r] + bias;
            s += (c < C) ? fmaxf(vv, 0.f) : 0.f;
        }
        s += __shfl_xor(s, 16);
        s += __shfl_xor(s, 32);
        if (g == 0) h_bf[b * TWO_D + j] = f2bf(s);
    }
}

// ---------------------------------------------------------------------------
// K_heads: MFMA GEMM mv = h @ [mean_W; var_W]^T + bias. (unchanged)
// ---------------------------------------------------------------------------
__global__ __launch_bounds__(256) void k_heads(
    const float* __restrict__ mean_W, const float* __restrict__ mean_b,
    const float* __restrict__ var_W, const float* __restrict__ var_b,
    const ushort_t* __restrict__ h_bf, float* __restrict__ mv)
{
    __shared__ __align__(16) ushort_t wt[2][64 * 40];
    const int tid = threadIdx.x;
    const int mblk = blockIdx.x & 3;
    const int nblk = blockIdx.x >> 2;
    const int n0 = nblk * 64;
    const float* Wsrc = (nblk < 4) ? mean_W : var_W;
    const float* bsrc = (nblk < 4) ? mean_b : var_b;
    const int nloc = (nblk & 3) * 64;
    const int wid = tid >> 6, lane = tid & 63;
    const int l15 = lane & 15, g = lane >> 4;

    const int r0 = tid >> 3, kq = tid & 7, r1 = r0 + 32;
    const float* src0 = Wsrc + (nloc + r0) * TWO_D + kq * 4;
    const float* src1 = Wsrc + (nloc + r1) * TWO_D + kq * 4;
    const int dst0 = r0 * 40 + kq * 4;
    const int dst1 = r1 * 40 + kq * 4;

    {
        const float4 na = *(const float4*)(src0);
        const float4 nb = *(const float4*)(src1);
        ushort4 pa, pb;
        pa.x = f2bf(na.x); pa.y = f2bf(na.y); pa.z = f2bf(na.z); pa.w = f2bf(na.w);
        pb.x = f2bf(nb.x); pb.y = f2bf(nb.y); pb.z = f2bf(nb.z); pb.w = f2bf(nb.w);
        *(ushort4*)(&wt[0][dst0]) = pa;
        *(ushort4*)(&wt[0][dst1]) = pb;
    }
    __syncthreads();

    const int rowA = mblk * 64 + wid * 16 + l15;
    f32x4 acc[4] = {};
    #pragma unroll 1
    for (int kk = 0; kk < 16; ++kk) {
        const int cur = kk & 1, nxt = cur ^ 1;
        float4 na, nb;
        if (kk < 15) {
            na = *(const float4*)(src0 + (kk + 1) * 32);
            nb = *(const float4*)(src1 + (kk + 1) * 32);
        }
        const bf16x8 A = *(const bf16x8*)(h_bf + rowA * TWO_D + kk * 32 + g * 8);
        bf16x8 Bf[4];
        #pragma unroll
        for (int vt = 0; vt < 4; ++vt)
            Bf[vt] = *(const bf16x8*)(&wt[cur][(vt * 16 + l15) * 40 + g * 8]);
        #pragma unroll
        for (int vt = 0; vt < 4; ++vt)
            acc[vt] = __builtin_amdgcn_mfma_f32_16x16x32_bf16(A, Bf[vt], acc[vt], 0, 0, 0);
        if (kk < 15) {
            ushort4 pa, pb;
            pa.x = f2bf(na.x); pa.y = f2bf(na.y); pa.z = f2bf(na.z); pa.w = f2bf(na.w);
            pb.x = f2bf(nb.x); pb.y = f2bf(nb.y); pb.z = f2bf(nb.z); pb.w = f2bf(nb.w);
            *(ushort4*)(&wt[nxt][dst0]) = pa;
            *(ushort4*)(&wt[nxt][dst1]) = pb;
        }
        __syncthreads();
    }

    const int rowBase = mblk * 64 + wid * 16;
    #pragma unroll
    for (int vt = 0; vt < 4; ++vt) {
        const int col = n0 + vt * 16 + l15;
        const float bias = bsrc[nloc + vt * 16 + l15];
        #pragma unroll
        for (int r = 0; r < 4; ++r) {
            const int row = rowBase + g * 4 + r;
            mv[row * TWO_D + col] = acc[vt][r] + bias;
        }
    }
}

// ---------------------------------------------------------------------------
// K_z: per-b: softplus, z (fp32->bf16), KL, ctx-logit sum. (unchanged)
// ---------------------------------------------------------------------------
__global__ __launch_bounds__(256) void k_z(
    const int* __restrict__ center_id, const int* __restrict__ context_ids,
    const float* __restrict__ prior_means_w, const float* __restrict__ prior_vars_w,
    const float* __restrict__ vocab_W, const float* __restrict__ vocab_b,
    const float* __restrict__ epsilon, const float* __restrict__ mv,
    ushort_t* __restrict__ z_bf, float* __restrict__ base)
{
    __shared__ float red[8];
    __shared__ int cids[C];
    const int b = blockIdx.x, tid = threadIdx.x;
    const int cid = center_id[b];
    if (tid < C) cids[tid] = context_ids[b * C + tid];
    __syncthreads();

    const int i = tid;
    const float mean = mv[b * TWO_D + i];
    const float a    = mv[b * TWO_D + D + i];
    const float var  = softplus_f(a);
    const float z    = mean + __expf(0.5f * var) * epsilon[i];
    z_bf[b * D + i]  = f2bf(z);

    const float pm = prior_means_w[cid * D + i];
    const float pv = softplus_f(prior_vars_w[cid * D + i]);
    const float dm = pm - mean;
    float klt = var / pv + dm * dm / pv - 1.f + __logf(pv) - __logf(var);

    float wsum = 0.f;
    #pragma unroll
    for (int c = 0; c < C; ++c) wsum += vocab_W[cids[c] * D + i];
    float p = z * wsum;

    klt = wave_reduce(klt);
    p = wave_reduce(p);
    const int wid = tid >> 6, lane = tid & 63;
    if (lane == 0) { red[wid] = klt; red[4 + wid] = p; }
    __syncthreads();
    if (tid == 0) {
        const float kl = 0.5f * (red[0] + red[1] + red[2] + red[3]);
        float cs = red[4] + red[5] + red[6] + red[7];
        #pragma unroll
        for (int c = 0; c < C; ++c) cs += vocab_b[cids[c]];
        base[b] = cs - kl;
    }
}

// ---------------------------------------------------------------------------
// K3 (rewritten): barrier-free, LDS-free logits GEMM + exp partial sums.
// Block = 256 thr (4 waves). Tile: 256 b x 32 v. Each wave: 4 bt x 2 vt.
// B fragments loaded straight from vocab_W (8 contiguous fp32 per lane =
// 2x float4, 128B-line cooperative across g-groups), cvt in-register,
// depth-2 rotating prefetch, fully unrolled K-loop, no __syncthreads.
// ---------------------------------------------------------------------------
__global__ __launch_bounds__(256) void k3_logits(
    const float* __restrict__ vocab_W, const float* __restrict__ vocab_b,
    const ushort_t* __restrict__ z_bf, float* __restrict__ partial)
{
    const int tid = threadIdx.x;
    const int blk = blockIdx.x;
    const int v0 = blk * VBLK;
    const int wid = tid >> 6, lane = tid & 63;
    const int l15 = lane & 15, g = lane >> 4;

    // per-lane B row pointers (clamped; invalid cols masked in epilogue)
    const float* bsrc[2];
    bool valid[2];
    float bias[2];
    #pragma unroll
    for (int vt = 0; vt < 2; ++vt) {
        const int v = v0 + vt * 16 + l15;
        valid[vt] = (v < V);
        const int vr = valid[vt] ? v : (V - 1);
        bsrc[vt] = vocab_W + vr * D + g * 8;
        bias[vt] = valid[vt] ? vocab_b[v] : 0.f;
    }
    const ushort_t* aptr = z_bf + (wid * 64 + l15) * D + g * 8;

    float4 st0[2][2], st1[2][2];    // two prefetch stages, [vt][half]
    #pragma unroll
    for (int vt = 0; vt < 2; ++vt) {
        st0[vt][0] = *(const float4*)(bsrc[vt]);
        st0[vt][1] = *(const float4*)(bsrc[vt] + 4);
        st1[vt][0] = *(const float4*)(bsrc[vt] + 32);
        st1[vt][1] = *(const float4*)(bsrc[vt] + 36);
    }

    f32x4 acc[4][2] = {};
    #pragma unroll
    for (int kk = 0; kk < 8; ++kk) {
        // A fragments for this k-step (z_bf is L1/L2-hot, 128 KB total)
        bf16x8 A[4];
        #pragma unroll
        for (int bt = 0; bt < 4; ++bt)
            A[bt] = *(const bf16x8*)(aptr + bt * 16 * D + kk * 32);

        bf16x8 Bf[2];
        // consume current stage, then reuse its registers for kk+2 prefetch
        #pragma unroll
        for (int par = 0; par < 2; ++par) {
            if ((kk & 1) == par) {
                float4 (&st)[2][2] = par ? st1 : st0;
                #pragma unroll
                for (int vt = 0; vt < 2; ++vt) {
                    const float4 x = st[vt][0], y = st[vt][1];
                    bf16x8 r;
                    r[0] = (__bf16)x.x; r[1] = (__bf16)x.y;
                    r[2] = (__bf16)x.z; r[3] = (__bf16)x.w;
                    r[4] = (__bf16)y.x; r[5] = (__bf16)y.y;
                    r[6] = (__bf16)y.z; r[7] = (__bf16)y.w;
                    Bf[vt] = r;
                }
                if (kk + 2 < 8) {
                    #pragma unroll
                    for (int vt = 0; vt < 2; ++vt) {
                        st[vt][0] = *(const float4*)(bsrc[vt] + (kk + 2) * 32);
                        st[vt][1] = *(const float4*)(bsrc[vt] + (kk + 2) * 32 + 4);
                    }
                }
            }
        }

        #pragma unroll
        for (int bt = 0; bt < 4; ++bt)
            #pragma unroll
            for (int vt = 0; vt < 2; ++vt)
                acc[bt][vt] = __builtin_amdgcn_mfma_f32_16x16x32_bf16(
                    A[bt], Bf[vt], acc[bt][vt], 0, 0, 0);
    }

    // epilogue: partial_b = sum over this block's valid v of exp(logit)
    #pragma unroll
    for (int bt = 0; bt < 4; ++bt) {
        #pragma unroll
        for (int r = 0; r < 4; ++r) {
            float s = 0.f;
            #pragma unroll
            for (int vt = 0; vt < 2; ++vt)
                s += valid[vt] ? __expf(acc[bt][vt][r] + bias[vt]) : 0.f;
            #pragma unroll
            for (int m = 1; m < 16; m <<= 1) s += __shfl_xor(s, m);
            if (l15 == 0) {
                const int brow = wid * 64 + bt * 16 + g * 4 + r;   // C/D: row=(lane>>4)*4+reg
                partial[brow * NBLK + blk] = s;
            }
        }
    }
}

// ---------------------------------------------------------------------------
// K4: per-b LSE over the NBLK partials; out_b = base_b - C*log(sum)
// ---------------------------------------------------------------------------
__global__ __launch_bounds__(256) void k4_lse(
    const float* __restrict__ partial, const float* __restrict__ base,
    float* __restrict__ outb)
{
    __shared__ float red[4];
    const int b = blockIdx.x, tid = threadIdx.x;
    float s = 0.f;
    for (int i = tid; i < NBLK; i += 256) s += partial[b * NBLK + i];
    s = wave_reduce(s);
    if ((tid & 63) == 0) red[tid >> 6] = s;
    __syncthreads();
    if (tid == 0) {
        const float tot = red[0] + red[1] + red[2] + red[3];
        outb[b] = base[b] - (float)C * __logf(tot);
    }
}

// ---------------------------------------------------------------------------
// K5: final 256 -> 1 reduce
// ---------------------------------------------------------------------------
__global__ __launch_bounds__(256) void k5_final(
    const float* __restrict__ outb, float* __restrict__ out)
{
    __shared__ float red[4];
    const int tid = threadIdx.x;
    float s = outb[tid];
    s = wave_reduce(s);
    if ((tid & 63) == 0) red[tid >> 6] = s;
    __syncthreads();
    if (tid == 0) out[0] = red[0] + red[1] + red[2] + red[3];
}

extern "C" void kernel_launch(void* const* d_in, const int* in_sizes, int n_in,
                              void* d_out, int out_size, void* d_ws, size_t ws_size,
                              hipStream_t stream)
{
    const int*   center_id     = (const int*)d_in[0];
    const int*   context_ids   = (const int*)d_in[1];
    const float* embeddings    = (const float*)d_in[2];
    const float* prior_means_w = (const float*)d_in[3];
    const float* prior_vars_w  = (const float*)d_in[4];
    const float* enc_W         = (const float*)d_in[5];
    const float* enc_b         = (const float*)d_in[6];
    const float* mean_W        = (const float*)d_in[7];
    const float* mean_b        = (const float*)d_in[8];
    const float* var_W         = (const float*)d_in[9];
    const float* var_b         = (const float*)d_in[10];
    const float* vocab_W       = (const float*)d_in[11];
    const float* vocab_b       = (const float*)d_in[12];
    const float* epsilon       = (const float*)d_in[13];

    // workspace layout (all fully rewritten every call)
    char* ws = (char*)d_ws;
    ushort_t* xbf     = (ushort_t*)ws;                            // 4 MB
    ws += (size_t)MPAD * TWO_D * 2;
    ushort_t* h_bf    = (ushort_t*)ws;                            // 256 KB
    ws += (size_t)B * TWO_D * 2;
    float*    mv      = (float*)ws;                               // 512 KB
    ws += (size_t)B * TWO_D * 4;
    ushort_t* z_bf    = (ushort_t*)ws;                            // 128 KB
    ws += (size_t)B * D * 2;
    float*    base    = (float*)ws;  ws += B * 4;
    float*    outb    = (float*)ws;  ws += B * 4;
    float*    partial = (float*)ws;                               // 256*1563*4 = 1.6 MB

    hipLaunchKernelGGL(k0_gather, dim3(2048), dim3(256), 0, stream,
                       center_id, context_ids, embeddings, xbf);
    hipLaunchKernelGGL(k_enc, dim3(512), dim3(256), 0, stream,
                       enc_W, enc_b, xbf, h_bf);
    hipLaunchKernelGGL(k_heads, dim3(32), dim3(256), 0, stream,
                       mean_W, mean_b, var_W, var_b, h_bf, mv);
    hipLaunchKernelGGL(k_z, dim3(B), dim3(256), 0, stream,
                       center_id, context_ids, prior_means_w, prior_vars_w,
                       vocab_W, vocab_b, epsilon, mv, z_bf, base);
    hipLaunchKernelGGL(k3_logits, dim3(NBLK), dim3(256), 0, stream,
                       vocab_W, vocab_b, z_bf, partial);
    hipLaunchKernelGGL(k4_lse, dim3(B), dim3(256), 0, stream, partial, base, outb);
    hipLaunchKernelGGL(k5_final, dim3(1), dim3(256), 0, stream, outb, (float*)d_out);
}

// Round 4
// 80.503 us; speedup vs baseline: 1.2335x; 1.2335x over previous
//
#include <hip/hip_runtime.h>
#include <hip/hip_bf16.h>

// Sizes fixed by the reference
#define V 50000
#define D 256
#define B 256
#define C 10
#define TWO_D 512
#define VBLK 32
#define NBLK ((V + VBLK - 1) / VBLK)   // 1563
#define MPAD 4096                      // 256 b * 16 (c padded 10 -> 16)

typedef __bf16 bf16x8 __attribute__((ext_vector_type(8)));
typedef float f32x4 __attribute__((ext_vector_type(4)));
typedef unsigned short ushort_t;
typedef unsigned int uint_t;

__device__ inline ushort_t f2bf(float f) {
    uint_t u = __builtin_bit_cast(uint_t, f);
    uint_t r = (u + 0x7FFFu + ((u >> 16) & 1u)) >> 16;
    return (ushort_t)r;
}

__device__ inline float softplus_f(float x) {
    return (x > 0.f) ? (x + log1pf(__expf(-x))) : log1pf(__expf(x));
}

__device__ inline float wave_reduce(float v) {
    #pragma unroll
    for (int m = 1; m < 64; m <<= 1) v += __shfl_xor(v, m);
    return v;
}

// ---------------------------------------------------------------------------
// K0: build X_bf [4096 x 512]: row m = b*16+c -> [center_b | ctx_{b,c}] bf16.
// ---------------------------------------------------------------------------
__global__ __launch_bounds__(256) void k0_gather(
    const int* __restrict__ center_id, const int* __restrict__ context_ids,
    const float* __restrict__ embeddings, ushort_t* __restrict__ xbf)
{
    const int idx = blockIdx.x * 256 + threadIdx.x;  // float4 index
    const int m = idx >> 7;
    const int q = idx & 127;
    const int k = q * 4;
    const int b = m >> 4, c = m & 15;
    ushort4 o;
    if (k < D) {
        const float4 v = *(const float4*)(embeddings + center_id[b] * D + k);
        o.x = f2bf(v.x); o.y = f2bf(v.y); o.z = f2bf(v.z); o.w = f2bf(v.w);
    } else if (c < C) {
        const float4 v = *(const float4*)(embeddings + context_ids[b * C + c] * D + (k - D));
        o.x = f2bf(v.x); o.y = f2bf(v.y); o.z = f2bf(v.z); o.w = f2bf(v.w);
    } else {
        o.x = 0; o.y = 0; o.z = 0; o.w = 0;
    }
    *(ushort4*)(xbf + idx * 4) = o;
}

// ---------------------------------------------------------------------------
// K_enc: MFMA GEMM + fused bias/relu/c-sum -> h_bf[b][e]. (unchanged, proven)
// ---------------------------------------------------------------------------
__global__ __launch_bounds__(256) void k_enc(
    const float* __restrict__ enc_W, const float* __restrict__ enc_b,
    const ushort_t* __restrict__ xbf, ushort_t* __restrict__ h_bf)
{
    __shared__ __align__(16) ushort_t wt[2][64 * 40];
    const int tid = threadIdx.x;
    const int mblk = blockIdx.x & 63;
    const int nblk = blockIdx.x >> 6;
    const int n0 = nblk * 64;
    const int wid = tid >> 6, lane = tid & 63;
    const int l15 = lane & 15, g = lane >> 4;

    const int r0 = tid >> 3, kq = tid & 7, r1 = r0 + 32;
    const float* src0 = enc_W + (n0 + r0) * TWO_D + kq * 4;
    const float* src1 = enc_W + (n0 + r1) * TWO_D + kq * 4;
    const int dst0 = r0 * 40 + kq * 4;
    const int dst1 = r1 * 40 + kq * 4;

    {
        const float4 na = *(const float4*)(src0);
        const float4 nb = *(const float4*)(src1);
        ushort4 pa, pb;
        pa.x = f2bf(na.x); pa.y = f2bf(na.y); pa.z = f2bf(na.z); pa.w = f2bf(na.w);
        pb.x = f2bf(nb.x); pb.y = f2bf(nb.y); pb.z = f2bf(nb.z); pb.w = f2bf(nb.w);
        *(ushort4*)(&wt[0][dst0]) = pa;
        *(ushort4*)(&wt[0][dst1]) = pb;
    }
    __syncthreads();

    const int rowA = mblk * 64 + wid * 16 + l15;
    f32x4 acc[4] = {};
    #pragma unroll 1
    for (int kk = 0; kk < 16; ++kk) {
        const int cur = kk & 1, nxt = cur ^ 1;
        float4 na, nb;
        if (kk < 15) {
            na = *(const float4*)(src0 + (kk + 1) * 32);
            nb = *(const float4*)(src1 + (kk + 1) * 32);
        }
        const bf16x8 A = *(const bf16x8*)(xbf + rowA * TWO_D + kk * 32 + g * 8);
        bf16x8 Bf[4];
        #pragma unroll
        for (int vt = 0; vt < 4; ++vt)
            Bf[vt] = *(const bf16x8*)(&wt[cur][(vt * 16 + l15) * 40 + g * 8]);
        #pragma unroll
        for (int vt = 0; vt < 4; ++vt)
            acc[vt] = __builtin_amdgcn_mfma_f32_16x16x32_bf16(A, Bf[vt], acc[vt], 0, 0, 0);
        if (kk < 15) {
            ushort4 pa, pb;
            pa.x = f2bf(na.x); pa.y = f2bf(na.y); pa.z = f2bf(na.z); pa.w = f2bf(na.w);
            pb.x = f2bf(nb.x); pb.y = f2bf(nb.y); pb.z = f2bf(nb.z); pb.w = f2bf(nb.w);
            *(ushort4*)(&wt[nxt][dst0]) = pa;
            *(ushort4*)(&wt[nxt][dst1]) = pb;
        }
        __syncthreads();
    }

    const int b = mblk * 4 + wid;
    #pragma unroll
    for (int vt = 0; vt < 4; ++vt) {
        const int j = n0 + vt * 16 + l15;
        const float bias = enc_b[j];
        float s = 0.f;
        #pragma unroll
        for (int r = 0; r < 4; ++r) {
            const int c = g * 4 + r;
            const float vv = acc[vt][r] + bias;
            s += (c < C) ? fmaxf(vv, 0.f) : 0.f;
        }
        s += __shfl_xor(s, 16);
        s += __shfl_xor(s, 32);
        if (g == 0) h_bf[b * TWO_D + j] = f2bf(s);
    }
}

// ---------------------------------------------------------------------------
// K_heads: MFMA GEMM mv = h @ [mean_W; var_W]^T + bias. (unchanged, proven)
// ---------------------------------------------------------------------------
__global__ __launch_bounds__(256) void k_heads(
    const float* __restrict__ mean_W, const float* __restrict__ mean_b,
    const float* __restrict__ var_W, const float* __restrict__ var_b,
    const ushort_t* __restrict__ h_bf, float* __restrict__ mv)
{
    __shared__ __align__(16) ushort_t wt[2][64 * 40];
    const int tid = threadIdx.x;
    const int mblk = blockIdx.x & 3;
    const int nblk = blockIdx.x >> 2;
    const int n0 = nblk * 64;
    const float* Wsrc = (nblk < 4) ? mean_W : var_W;
    const float* bsrc = (nblk < 4) ? mean_b : var_b;
    const int nloc = (nblk & 3) * 64;
    const int wid = tid >> 6, lane = tid & 63;
    const int l15 = lane & 15, g = lane >> 4;

    const int r0 = tid >> 3, kq = tid & 7, r1 = r0 + 32;
    const float* src0 = Wsrc + (nloc + r0) * TWO_D + kq * 4;
    const float* src1 = Wsrc + (nloc + r1) * TWO_D + kq * 4;
    const int dst0 = r0 * 40 + kq * 4;
    const int dst1 = r1 * 40 + kq * 4;

    {
        const float4 na = *(const float4*)(src0);
        const float4 nb = *(const float4*)(src1);
        ushort4 pa, pb;
        pa.x = f2bf(na.x); pa.y = f2bf(na.y); pa.z = f2bf(na.z); pa.w = f2bf(na.w);
        pb.x = f2bf(nb.x); pb.y = f2bf(nb.y); pb.z = f2bf(nb.z); pb.w = f2bf(nb.w);
        *(ushort4*)(&wt[0][dst0]) = pa;
        *(ushort4*)(&wt[0][dst1]) = pb;
    }
    __syncthreads();

    const int rowA = mblk * 64 + wid * 16 + l15;
    f32x4 acc[4] = {};
    #pragma unroll 1
    for (int kk = 0; kk < 16; ++kk) {
        const int cur = kk & 1, nxt = cur ^ 1;
        float4 na, nb;
        if (kk < 15) {
            na = *(const float4*)(src0 + (kk + 1) * 32);
            nb = *(const float4*)(src1 + (kk + 1) * 32);
        }
        const bf16x8 A = *(const bf16x8*)(h_bf + rowA * TWO_D + kk * 32 + g * 8);
        bf16x8 Bf[4];
        #pragma unroll
        for (int vt = 0; vt < 4; ++vt)
            Bf[vt] = *(const bf16x8*)(&wt[cur][(vt * 16 + l15) * 40 + g * 8]);
        #pragma unroll
        for (int vt = 0; vt < 4; ++vt)
            acc[vt] = __builtin_amdgcn_mfma_f32_16x16x32_bf16(A, Bf[vt], acc[vt], 0, 0, 0);
        if (kk < 15) {
            ushort4 pa, pb;
            pa.x = f2bf(na.x); pa.y = f2bf(na.y); pa.z = f2bf(na.z); pa.w = f2bf(na.w);
            pb.x = f2bf(nb.x); pb.y = f2bf(nb.y); pb.z = f2bf(nb.z); pb.w = f2bf(nb.w);
            *(ushort4*)(&wt[nxt][dst0]) = pa;
            *(ushort4*)(&wt[nxt][dst1]) = pb;
        }
        __syncthreads();
    }

    const int rowBase = mblk * 64 + wid * 16;
    #pragma unroll
    for (int vt = 0; vt < 4; ++vt) {
        const int col = n0 + vt * 16 + l15;
        const float bias = bsrc[nloc + vt * 16 + l15];
        #pragma unroll
        for (int r = 0; r < 4; ++r) {
            const int row = rowBase + g * 4 + r;
            mv[row * TWO_D + col] = acc[vt][r] + bias;
        }
    }
}

// ---------------------------------------------------------------------------
// K_z: per-b: softplus, z (fp32->bf16), KL, ctx-logit sum. (unchanged, proven)
// ---------------------------------------------------------------------------
__global__ __launch_bounds__(256) void k_z(
    const int* __restrict__ center_id, const int* __restrict__ context_ids,
    const float* __restrict__ prior_means_w, const float* __restrict__ prior_vars_w,
    const float* __restrict__ vocab_W, const float* __restrict__ vocab_b,
    const float* __restrict__ epsilon, const float* __restrict__ mv,
    ushort_t* __restrict__ z_bf, float* __restrict__ base)
{
    __shared__ float red[8];
    __shared__ int cids[C];
    const int b = blockIdx.x, tid = threadIdx.x;
    const int cid = center_id[b];
    if (tid < C) cids[tid] = context_ids[b * C + tid];
    __syncthreads();

    const int i = tid;
    const float mean = mv[b * TWO_D + i];
    const float a    = mv[b * TWO_D + D + i];
    const float var  = softplus_f(a);
    const float z    = mean + __expf(0.5f * var) * epsilon[i];
    z_bf[b * D + i]  = f2bf(z);

    const float pm = prior_means_w[cid * D + i];
    const float pv = softplus_f(prior_vars_w[cid * D + i]);
    const float dm = pm - mean;
    float klt = var / pv + dm * dm / pv - 1.f + __logf(pv) - __logf(var);

    float wsum = 0.f;
    #pragma unroll
    for (int c = 0; c < C; ++c) wsum += vocab_W[cids[c] * D + i];
    float p = z * wsum;

    klt = wave_reduce(klt);
    p = wave_reduce(p);
    const int wid = tid >> 6, lane = tid & 63;
    if (lane == 0) { red[wid] = klt; red[4 + wid] = p; }
    __syncthreads();
    if (tid == 0) {
        const float kl = 0.5f * (red[0] + red[1] + red[2] + red[3]);
        float cs = red[4] + red[5] + red[6] + red[7];
        #pragma unroll
        for (int c = 0; c < C; ++c) cs += vocab_b[cids[c]];
        base[b] = cs - kl;
    }
}

// ---------------------------------------------------------------------------
// K3 (v3): one-burst staging + single barrier + barrier-free MFMA.
// Block = 256 thr (4 waves), tile 256 b x 32 v, grid = 1563.
// Phase 1: 8 independent float4 loads/thread stage the 32x256 vocab tile as
//   bf16 into ldsB[kk][row][32] (u-linear writes: wave-contiguous, 0-conflict).
// Phase 2: 8 unrolled k-steps; A (z_bf, L2-hot) and B (ds_read, each instr
//   covers contiguous 1KB -> 0-conflict) prefetched depth-1, 8 MFMA/step.
// __launch_bounds__(256,4): VGPR<=128 -> 4 blocks/CU.
// ---------------------------------------------------------------------------
__global__ __launch_bounds__(256, 4) void k3_logits(
    const float* __restrict__ vocab_W, const float* __restrict__ vocab_b,
    const ushort_t* __restrict__ z_bf, float* __restrict__ partial)
{
    __shared__ __align__(16) ushort_t ldsB[VBLK * D];   // [kk][row][32] = 16 KB

    const int tid = threadIdx.x;
    const int blk = blockIdx.x;
    const int v0 = blk * VBLK;
    const int wid = tid >> 6, lane = tid & 63;
    const int l15 = lane & 15, g = lane >> 4;

    // ---- phase 1: stage tile. u = j*256+tid; kk=u>>8, row=(u>>3)&31, kq=u&7
    float4 st[8];
    #pragma unroll
    for (int j = 0; j < 8; ++j) {
        const int u = j * 256 + tid;
        const int kk = u >> 8, row = (u >> 3) & 31, kq = u & 7;
        const int gr = min(v0 + row, V - 1);
        st[j] = *(const float4*)(vocab_W + gr * D + kk * 32 + kq * 4);
    }
    #pragma unroll
    for (int j = 0; j < 8; ++j) {
        const int u = j * 256 + tid;
        ushort4 p;
        p.x = f2bf(st[j].x); p.y = f2bf(st[j].y);
        p.z = f2bf(st[j].z); p.w = f2bf(st[j].w);
        *(ushort4*)(ldsB + u * 4) = p;                  // byte offset u*8
    }
    __syncthreads();

    // ---- phase 2: MFMA, no barriers. A rows: wid*64 + bt*16 + l15.
    const ushort_t* aptr = z_bf + (wid * 64 + l15) * D + g * 8;

    bf16x8 A[2][4], Bf[2][2];
    #pragma unroll
    for (int bt = 0; bt < 4; ++bt)
        A[0][bt] = *(const bf16x8*)(aptr + bt * 16 * D);
    #pragma unroll
    for (int vt = 0; vt < 2; ++vt)
        Bf[0][vt] = *(const bf16x8*)(ldsB + (vt * 16 + l15) * 32 + g * 8);

    f32x4 acc[4][2] = {};
    #pragma unroll
    for (int kk = 0; kk < 8; ++kk) {
        const int cur = kk & 1, nxt = cur ^ 1;
        if (kk < 7) {
            #pragma unroll
            for (int bt = 0; bt < 4; ++bt)
                A[nxt][bt] = *(const bf16x8*)(aptr + bt * 16 * D + (kk + 1) * 32);
            #pragma unroll
            for (int vt = 0; vt < 2; ++vt)
                Bf[nxt][vt] = *(const bf16x8*)(ldsB + (kk + 1) * 1024
                                               + (vt * 16 + l15) * 32 + g * 8);
        }
        #pragma unroll
        for (int bt = 0; bt < 4; ++bt)
            #pragma unroll
            for (int vt = 0; vt < 2; ++vt)
                acc[bt][vt] = __builtin_amdgcn_mfma_f32_16x16x32_bf16(
                    A[cur][bt], Bf[cur][vt], acc[bt][vt], 0, 0, 0);
    }

    // ---- epilogue: partial_b = sum over this block's valid v of exp(logit)
    bool valid[2];
    float bias[2];
    #pragma unroll
    for (int vt = 0; vt < 2; ++vt) {
        const int v = v0 + vt * 16 + l15;
        valid[vt] = (v < V);
        bias[vt] = valid[vt] ? vocab_b[v] : 0.f;
    }
    #pragma unroll
    for (int bt = 0; bt < 4; ++bt) {
        #pragma unroll
        for (int r = 0; r < 4; ++r) {
            float s = 0.f;
            #pragma unroll
            for (int vt = 0; vt < 2; ++vt)
                s += valid[vt] ? __expf(acc[bt][vt][r] + bias[vt]) : 0.f;
            #pragma unroll
            for (int m = 1; m < 16; m <<= 1) s += __shfl_xor(s, m);
            if (l15 == 0) {
                const int brow = wid * 64 + bt * 16 + g * 4 + r;   // C/D: row=(lane>>4)*4+reg
                partial[brow * NBLK + blk] = s;
            }
        }
    }
}

// ---------------------------------------------------------------------------
// K4: per-b LSE over the NBLK partials; out_b = base_b - C*log(sum)
// ---------------------------------------------------------------------------
__global__ __launch_bounds__(256) void k4_lse(
    const float* __restrict__ partial, const float* __restrict__ base,
    float* __restrict__ outb)
{
    __shared__ float red[4];
    const int b = blockIdx.x, tid = threadIdx.x;
    float s = 0.f;
    for (int i = tid; i < NBLK; i += 256) s += partial[b * NBLK + i];
    s = wave_reduce(s);
    if ((tid & 63) == 0) red[tid >> 6] = s;
    __syncthreads();
    if (tid == 0) {
        const float tot = red[0] + red[1] + red[2] + red[3];
        outb[b] = base[b] - (float)C * __logf(tot);
    }
}

// ---------------------------------------------------------------------------
// K5: final 256 -> 1 reduce
// ---------------------------------------------------------------------------
__global__ __launch_bounds__(256) void k5_final(
    const float* __restrict__ outb, float* __restrict__ out)
{
    __shared__ float red[4];
    const int tid = threadIdx.x;
    float s = outb[tid];
    s = wave_reduce(s);
    if ((tid & 63) == 0) red[tid >> 6] = s;
    __syncthreads();
    if (tid == 0) out[0] = red[0] + red[1] + red[2] + red[3];
}

extern "C" void kernel_launch(void* const* d_in, const int* in_sizes, int n_in,
                              void* d_out, int out_size, void* d_ws, size_t ws_size,
                              hipStream_t stream)
{
    const int*   center_id     = (const int*)d_in[0];
    const int*   context_ids   = (const int*)d_in[1];
    const float* embeddings    = (const float*)d_in[2];
    const float* prior_means_w = (const float*)d_in[3];
    const float* prior_vars_w  = (const float*)d_in[4];
    const float* enc_W         = (const float*)d_in[5];
    const float* enc_b         = (const float*)d_in[6];
    const float* mean_W        = (const float*)d_in[7];
    const float* mean_b        = (const float*)d_in[8];
    const float* var_W         = (const float*)d_in[9];
    const float* var_b         = (const float*)d_in[10];
    const float* vocab_W       = (const float*)d_in[11];
    const float* vocab_b       = (const float*)d_in[12];
    const float* epsilon       = (const float*)d_in[13];

    // workspace layout (all fully rewritten every call)
    char* ws = (char*)d_ws;
    ushort_t* xbf     = (ushort_t*)ws;                            // 4 MB
    ws += (size_t)MPAD * TWO_D * 2;
    ushort_t* h_bf    = (ushort_t*)ws;                            // 256 KB
    ws += (size_t)B * TWO_D * 2;
    float*    mv      = (float*)ws;                               // 512 KB
    ws += (size_t)B * TWO_D * 4;
    ushort_t* z_bf    = (ushort_t*)ws;                            // 128 KB
    ws += (size_t)B * D * 2;
    float*    base    = (float*)ws;  ws += B * 4;
    float*    outb    = (float*)ws;  ws += B * 4;
    float*    partial = (float*)ws;                               // 256*1563*4 = 1.6 MB

    hipLaunchKernelGGL(k0_gather, dim3(2048), dim3(256), 0, stream,
                       center_id, context_ids, embeddings, xbf);
    hipLaunchKernelGGL(k_enc, dim3(512), dim3(256), 0, stream,
                       enc_W, enc_b, xbf, h_bf);
    hipLaunchKernelGGL(k_heads, dim3(32), dim3(256), 0, stream,
                       mean_W, mean_b, var_W, var_b, h_bf, mv);
    hipLaunchKernelGGL(k_z, dim3(B), dim3(256), 0, stream,
                       center_id, context_ids, prior_means_w, prior_vars_w,
                       vocab_W, vocab_b, epsilon, mv, z_bf, base);
    hipLaunchKernelGGL(k3_logits, dim3(NBLK), dim3(256), 0, stream,
                       vocab_W, vocab_b, z_bf, partial);
    hipLaunchKernelGGL(k4_lse, dim3(B), dim3(256), 0, stream, partial, base, outb);
    hipLaunchKernelGGL(k5_final, dim3(1), dim3(256), 0, stream, outb, (float*)d_out);
}